// Round 7
// baseline (198.966 us; speedup 1.0000x reference)
//
#include <hip/hip_runtime.h>
#include <math.h>

#define BB 64
#define SS 2048
#define HH 1024
#define PP 8
#define SPLIT 16
#define ROWS (SS / SPLIT)   // 128
#define GEMM_BLOCKS 256

typedef float vf4 __attribute__((ext_vector_type(4)));

// ---------------- Kernel 1: partial mean-pool over S ----------------
// grid = BB*SPLIT (1024) blocks, 256 threads. R4-exact loop: NT loads, 2 accum
// chains, s+=2, unroll 4 (proven 102.6us config). Block 0 also zeroes the
// done-counter for the gemm's last-block head fusion (stream-ordered).
__global__ __launch_bounds__(256) void pool_partial_k(const float* __restrict__ hs,
                                                      float* __restrict__ part,
                                                      unsigned int* __restrict__ done) {
    if (blockIdx.x == 0 && threadIdx.x == 0) atomicExch(done, 0u);
    int blk = blockIdx.x;
    int b  = blk / SPLIT;
    int sp = blk % SPLIT;
    int t  = threadIdx.x;
    const vf4* base = reinterpret_cast<const vf4*>(
        hs + (size_t)b * SS * HH + (size_t)sp * ROWS * HH) + t;
    vf4 acc0 = (vf4)0.f;
    vf4 acc1 = (vf4)0.f;
    #pragma unroll 4
    for (int s = 0; s < ROWS; s += 2) {
        vf4 v0 = __builtin_nontemporal_load(&base[(size_t)(s + 0) * (HH / 4)]);
        vf4 v1 = __builtin_nontemporal_load(&base[(size_t)(s + 1) * (HH / 4)]);
        acc0 += v0;
        acc1 += v1;
    }
    reinterpret_cast<vf4*>(part)[(size_t)blk * (HH / 4) + t] = acc0 + acc1;
}

// ------- Kernel 2: fused pool-finish + GEMM1 + SiLU + (last block) head -------
// grid = 256 blocks: (bg 0..15) x (oc 0..15). 512 threads = 8 waves.
// Note: same-oc blocks (blk%8==oc%8) land on one XCD -> W1 chunk is L2-resident.
// After hbuf writes, blocks count up; the 256th block computes logits/softmax/
// bit-allocation for all 64 batch rows (saves the head launch + gap).
__global__ __launch_bounds__(512) void gemm_fused_k(const float* __restrict__ part,
                                                    const float* __restrict__ W1,
                                                    const float* __restrict__ b1,
                                                    const float* __restrict__ W2,
                                                    const float* __restrict__ b2,
                                                    const float* __restrict__ temp_p,
                                                    const int* __restrict__ budget_p,
                                                    float* __restrict__ hbuf,
                                                    float* __restrict__ out,
                                                    unsigned int* __restrict__ done) {
    int bg = blockIdx.x >> 4;
    int oc = blockIdx.x & 15;
    int t  = threadIdx.x;            // 0..511
    int wave = t >> 6, lane = t & 63;
    __shared__ vf4 spool[4][HH / 4];
    __shared__ float slog[BB][PP];
    __shared__ unsigned int slast;

    // ---- pool finish: pooled rows 4*bg..4*bg+3 from partials ----
    {
        int c  = t & 255;
        int r0 = t >> 8;             // 0..1
        #pragma unroll
        for (int rr = 0; rr < 2; ++rr) {
            int r = r0 + 2 * rr;     // 0..3
            int b = bg * 4 + r;
            const vf4* pb = reinterpret_cast<const vf4*>(part) +
                            (size_t)b * SPLIT * (HH / 4) + c;
            vf4 s = (vf4)0.f;
            #pragma unroll
            for (int sp = 0; sp < SPLIT; ++sp)
                s += pb[(size_t)sp * (HH / 4)];
            spool[r][c] = s * (1.0f / (float)SS);
        }
    }
    __syncthreads();

    // ---- GEMM: wave covers outputs wave*8..wave*8+7; 16-lane K-split ----
    {
        int g = lane >> 4;               // 0..3: output offset within quad
        int q = lane & 15;               // K-split index
        int o0 = oc * 64 + wave * 8 + g;
        int o1 = o0 + 4;
        const vf4* w0 = reinterpret_cast<const vf4*>(W1 + (size_t)o0 * HH) + q;
        const vf4* w1 = reinterpret_cast<const vf4*>(W1 + (size_t)o1 * HH) + q;
        float a0 = 0.f, a1 = 0.f, a2 = 0.f, a3 = 0.f;
        float c0 = 0.f, c1 = 0.f, c2 = 0.f, c3 = 0.f;
        #pragma unroll
        for (int k = 0; k < 16; ++k) {
            vf4 p0 = spool[0][q + 16 * k];
            vf4 p1 = spool[1][q + 16 * k];
            vf4 p2 = spool[2][q + 16 * k];
            vf4 p3 = spool[3][q + 16 * k];
            vf4 wa = w0[16 * k];
            vf4 wb = w1[16 * k];
            a0 += wa.x * p0.x + wa.y * p0.y + wa.z * p0.z + wa.w * p0.w;
            a1 += wa.x * p1.x + wa.y * p1.y + wa.z * p1.z + wa.w * p1.w;
            a2 += wa.x * p2.x + wa.y * p2.y + wa.z * p2.z + wa.w * p2.w;
            a3 += wa.x * p3.x + wa.y * p3.y + wa.z * p3.z + wa.w * p3.w;
            c0 += wb.x * p0.x + wb.y * p0.y + wb.z * p0.z + wb.w * p0.w;
            c1 += wb.x * p1.x + wb.y * p1.y + wb.z * p1.z + wb.w * p1.w;
            c2 += wb.x * p2.x + wb.y * p2.y + wb.z * p2.z + wb.w * p2.w;
            c3 += wb.x * p3.x + wb.y * p3.y + wb.z * p3.z + wb.w * p3.w;
        }
        #pragma unroll
        for (int off = 1; off < 16; off <<= 1) {
            a0 += __shfl_xor(a0, off); a1 += __shfl_xor(a1, off);
            a2 += __shfl_xor(a2, off); a3 += __shfl_xor(a3, off);
            c0 += __shfl_xor(c0, off); c1 += __shfl_xor(c1, off);
            c2 += __shfl_xor(c2, off); c3 += __shfl_xor(c3, off);
        }
        if (q < 4) {
            float sa = (q == 0) ? a0 : ((q == 1) ? a1 : ((q == 2) ? a2 : a3));
            float sc = (q == 0) ? c0 : ((q == 1) ? c1 : ((q == 2) ? c2 : c3));
            int b = bg * 4 + q;
            float za = sa + b1[o0];
            float zc = sc + b1[o1];
            hbuf[(size_t)b * HH + o0] = za / (1.f + expf(-za));
            hbuf[(size_t)b * HH + o1] = zc / (1.f + expf(-zc));
        }
    }

    // ---- last-block election (release hbuf, count, acquire) ----
    __threadfence();                 // each thread releases its hbuf stores
    __syncthreads();
    if (t == 0) {
        unsigned int old = atomicAdd(done, 1u);   // device-scope
        slast = (old == GEMM_BLOCKS - 1) ? 1u : 0u;
        if (slast) atomicExch(done, 0u);          // reset for next replay
    }
    __syncthreads();
    if (!slast) return;
    __threadfence();                 // acquire: see all blocks' hbuf stores

    // ---- head, phase 1: logits[64][8] ----
    // wave w handles b rows w*8..w*8+7; lane = p*8+q (p logit, q K-split of 128).
    {
        int p = lane >> 3, q = lane & 7;
        const vf4* w2r = reinterpret_cast<const vf4*>(W2 + (size_t)p * HH) + q * 32;
        for (int bb = 0; bb < 8; ++bb) {
            int b = wave * 8 + bb;
            const vf4* hr = reinterpret_cast<const vf4*>(hbuf + (size_t)b * HH) + q * 32;
            float s = 0.f;
            #pragma unroll
            for (int j = 0; j < 32; ++j) {
                vf4 hv = hr[j];
                vf4 wv = w2r[j];
                s += wv.x * hv.x + wv.y * hv.y + wv.z * hv.z + wv.w * hv.w;
            }
            s += __shfl_xor(s, 1);
            s += __shfl_xor(s, 2);
            s += __shfl_xor(s, 4);
            if (q == 0) slog[b][p] = s + b2[p];
        }
    }
    __syncthreads();

    // ---- head, phase 2: epilogue — wave 0, lane b handles batch row b ----
    if (wave != 0) return;
    {
        int b = lane;                // 0..63
        float logit[PP];
        #pragma unroll
        for (int p = 0; p < PP; ++p) logit[p] = slog[b][p];
        float temp = fminf(fmaxf(temp_p[0], 0.1f), 5.0f);
        float budget = (float)budget_p[0];
        float inv_t = 1.0f / temp;
        float m = -INFINITY;
        #pragma unroll
        for (int p = 0; p < PP; ++p) { logit[p] *= inv_t; m = fmaxf(m, logit[p]); }
        float e[PP], se = 0.f;
        #pragma unroll
        for (int p = 0; p < PP; ++p) { e[p] = expf(logit[p] - m); se += e[p]; }
        float probs[PP];
        float inv_se = 1.0f / se;
        #pragma unroll
        for (int p = 0; p < PP; ++p) probs[p] = e[p] * inv_se;

        float x[PP], sx = 0.f;
        #pragma unroll
        for (int p = 0; p < PP; ++p) {
            x[p] = fminf(fmaxf(probs[p] * budget, 2.0f), 8.0f);
            sx += x[p];
        }
        float r = budget / (sx + 1e-8f);
        float bits[PP], sb = 0.f;
        #pragma unroll
        for (int p = 0; p < PP; ++p) {
            x[p] *= r;
            bits[p] = rintf(x[p]);   // round-half-even == jnp.round
            sb += bits[p];
        }
        float diff = truncf(budget - sb);
        if (diff != 0.f) {
            int idx = 0;
            if (diff > 0.f) {
                float best = bits[0];
                for (int p = 1; p < PP; ++p) if (bits[p] > best) { best = bits[p]; idx = p; }
            } else {
                float best = bits[0];
                for (int p = 1; p < PP; ++p) if (bits[p] < best) { best = bits[p]; idx = p; }
            }
            bits[idx] = fminf(fmaxf(bits[idx] + diff, 2.0f), 8.0f);
        }
        #pragma unroll
        for (int p = 0; p < PP; ++p) {
            out[b * PP + p] = bits[p];
            out[BB * PP + b * PP + p] = probs[p];
        }
    }
}

extern "C" void kernel_launch(void* const* d_in, const int* in_sizes, int n_in,
                              void* d_out, int out_size, void* d_ws, size_t ws_size,
                              hipStream_t stream) {
    const float* hs     = (const float*)d_in[0];
    const float* W1     = (const float*)d_in[1];
    const float* b1     = (const float*)d_in[2];
    const float* W2     = (const float*)d_in[3];
    const float* b2     = (const float*)d_in[4];
    const float* temp   = (const float*)d_in[5];
    const int*   budget = (const int*)d_in[6];
    float* out = (float*)d_out;

    float* ws   = (float*)d_ws;
    float* part = ws;                                     // BB*SPLIT*HH floats (4 MB)
    float* hbuf = ws + (size_t)BB * SPLIT * HH;           // BB*HH floats
    unsigned int* done = (unsigned int*)(ws + (size_t)BB * SPLIT * HH + (size_t)BB * HH + 64);

    hipLaunchKernelGGL(pool_partial_k, dim3(BB * SPLIT), dim3(256), 0, stream, hs, part, done);
    hipLaunchKernelGGL(gemm_fused_k,   dim3(GEMM_BLOCKS), dim3(512), 0, stream,
                       part, W1, b1, W2, b2, temp, budget, hbuf, out, done);
}

// Round 8
// 107.454 us; speedup vs baseline: 1.8516x; 1.8516x over previous
//
#include <hip/hip_runtime.h>
#include <math.h>

#define BB 64
#define SS 2048
#define HH 1024
#define PP 8
#define SPLIT 16
#define ROWS (SS / SPLIT)   // 128

typedef float vf4 __attribute__((ext_vector_type(4)));

// ---------------- Kernel 1: partial mean-pool over S ----------------
// R4-EXACT loop (measured best: 102.6us total): NT loads, 2 accumulator
// chains, s+=2, unroll 4. NT is worth ~12-17us vs cached (R5/R6 A/B).
// Do NOT fuse the head via device fences: R7's threadfence+atomic fusion
// cost +92us (L2 writeback storms).
__global__ __launch_bounds__(256) void pool_partial_k(const float* __restrict__ hs,
                                                      float* __restrict__ part) {
    int blk = blockIdx.x;
    int b  = blk / SPLIT;
    int sp = blk % SPLIT;
    int t  = threadIdx.x;
    const vf4* base = reinterpret_cast<const vf4*>(
        hs + (size_t)b * SS * HH + (size_t)sp * ROWS * HH) + t;
    vf4 acc0 = (vf4)0.f;
    vf4 acc1 = (vf4)0.f;
    #pragma unroll 4
    for (int s = 0; s < ROWS; s += 2) {
        vf4 v0 = __builtin_nontemporal_load(&base[(size_t)(s + 0) * (HH / 4)]);
        vf4 v1 = __builtin_nontemporal_load(&base[(size_t)(s + 1) * (HH / 4)]);
        acc0 += v0;
        acc1 += v1;
    }
    reinterpret_cast<vf4*>(part)[(size_t)blk * (HH / 4) + t] = acc0 + acc1;
}

// ---------------- Kernel 2: fused pool-finish + GEMM1 + SiLU ----------------
// grid = 256 blocks: (bg 0..15) x (oc 0..15). 512 threads = 8 waves.
// Same-oc blocks land on one XCD -> W1 chunk L2-resident by construction.
// Inner loop: 4 spool LDS reads shared across both output rows (hoisted; 64
// ds_read_b128/thread), 8 named accumulators.
__global__ __launch_bounds__(512) void gemm_fused_k(const float* __restrict__ part,
                                                    const float* __restrict__ W1,
                                                    const float* __restrict__ b1,
                                                    float* __restrict__ hbuf) {
    int bg = blockIdx.x >> 4;
    int oc = blockIdx.x & 15;
    int t  = threadIdx.x;            // 0..511
    int wave = t >> 6, lane = t & 63;
    __shared__ vf4 spool[4][HH / 4];

    // ---- pool finish: pooled rows 4*bg..4*bg+3 from partials ----
    {
        int c  = t & 255;
        int r0 = t >> 8;             // 0..1
        #pragma unroll
        for (int rr = 0; rr < 2; ++rr) {
            int r = r0 + 2 * rr;     // 0..3
            int b = bg * 4 + r;
            const vf4* pb = reinterpret_cast<const vf4*>(part) +
                            (size_t)b * SPLIT * (HH / 4) + c;
            vf4 s = (vf4)0.f;
            #pragma unroll
            for (int sp = 0; sp < SPLIT; ++sp)
                s += pb[(size_t)sp * (HH / 4)];
            spool[r][c] = s * (1.0f / (float)SS);
        }
    }
    __syncthreads();

    // ---- GEMM: wave covers outputs wave*8..wave*8+7; 16-lane K-split ----
    int g = lane >> 4;               // 0..3: output offset within quad
    int q = lane & 15;               // K-split index
    int o0 = oc * 64 + wave * 8 + g;
    int o1 = o0 + 4;
    const vf4* w0 = reinterpret_cast<const vf4*>(W1 + (size_t)o0 * HH) + q;
    const vf4* w1 = reinterpret_cast<const vf4*>(W1 + (size_t)o1 * HH) + q;
    float a0 = 0.f, a1 = 0.f, a2 = 0.f, a3 = 0.f;   // o0 x batch 0..3
    float c0 = 0.f, c1 = 0.f, c2 = 0.f, c3 = 0.f;   // o1 x batch 0..3
    #pragma unroll
    for (int k = 0; k < 16; ++k) {
        vf4 p0 = spool[0][q + 16 * k];
        vf4 p1 = spool[1][q + 16 * k];
        vf4 p2 = spool[2][q + 16 * k];
        vf4 p3 = spool[3][q + 16 * k];
        vf4 wa = w0[16 * k];
        vf4 wb = w1[16 * k];
        a0 += wa.x * p0.x + wa.y * p0.y + wa.z * p0.z + wa.w * p0.w;
        a1 += wa.x * p1.x + wa.y * p1.y + wa.z * p1.z + wa.w * p1.w;
        a2 += wa.x * p2.x + wa.y * p2.y + wa.z * p2.z + wa.w * p2.w;
        a3 += wa.x * p3.x + wa.y * p3.y + wa.z * p3.z + wa.w * p3.w;
        c0 += wb.x * p0.x + wb.y * p0.y + wb.z * p0.z + wb.w * p0.w;
        c1 += wb.x * p1.x + wb.y * p1.y + wb.z * p1.z + wb.w * p1.w;
        c2 += wb.x * p2.x + wb.y * p2.y + wb.z * p2.z + wb.w * p2.w;
        c3 += wb.x * p3.x + wb.y * p3.y + wb.z * p3.z + wb.w * p3.w;
    }
    #pragma unroll
    for (int off = 1; off < 16; off <<= 1) {
        a0 += __shfl_xor(a0, off); a1 += __shfl_xor(a1, off);
        a2 += __shfl_xor(a2, off); a3 += __shfl_xor(a3, off);
        c0 += __shfl_xor(c0, off); c1 += __shfl_xor(c1, off);
        c2 += __shfl_xor(c2, off); c3 += __shfl_xor(c3, off);
    }
    if (q < 4) {                     // lane q writes batch row q (named select)
        float sa = (q == 0) ? a0 : ((q == 1) ? a1 : ((q == 2) ? a2 : a3));
        float sc = (q == 0) ? c0 : ((q == 1) ? c1 : ((q == 2) ? c2 : c3));
        int b = bg * 4 + q;
        float za = sa + b1[o0];
        float zc = sc + b1[o1];
        hbuf[(size_t)b * HH + o0] = za / (1.f + expf(-za));
        hbuf[(size_t)b * HH + o1] = zc / (1.f + expf(-zc));
    }
}

// ---------------- Kernel 3: logits, softmax, bit allocation ----------------
// grid = BB blocks, 256 threads (4 waves). Wave w computes logits p=2w,2w+1.
__global__ __launch_bounds__(256) void head_k(const float* __restrict__ hbuf,
                                              const float* __restrict__ W2,
                                              const float* __restrict__ b2,
                                              const float* __restrict__ temp_p,
                                              const int* __restrict__ budget_p,
                                              float* __restrict__ out) {
    int b = blockIdx.x;
    int t = threadIdx.x;
    int wave = t >> 6, lane = t & 63;
    __shared__ float slog[PP];

    {
        const vf4* hrow = reinterpret_cast<const vf4*>(hbuf + (size_t)b * HH);
        int p0 = wave * 2, p1 = wave * 2 + 1;
        const vf4* w0 = reinterpret_cast<const vf4*>(W2 + (size_t)p0 * HH);
        const vf4* w1 = reinterpret_cast<const vf4*>(W2 + (size_t)p1 * HH);
        float s0 = 0.f, s1 = 0.f;
        #pragma unroll
        for (int k = 0; k < 4; ++k) {
            vf4 hv = hrow[lane + 64 * k];
            vf4 a = w0[lane + 64 * k];
            vf4 c = w1[lane + 64 * k];
            s0 += a.x * hv.x + a.y * hv.y + a.z * hv.z + a.w * hv.w;
            s1 += c.x * hv.x + c.y * hv.y + c.z * hv.z + c.w * hv.w;
        }
        #pragma unroll
        for (int off = 32; off; off >>= 1) {
            s0 += __shfl_xor(s0, off);
            s1 += __shfl_xor(s1, off);
        }
        if (lane == 0) {
            slog[p0] = s0 + b2[p0];
            slog[p1] = s1 + b2[p1];
        }
    }
    __syncthreads();
    if (wave != 0) return;

    float logit[PP];
    #pragma unroll
    for (int p = 0; p < PP; ++p) logit[p] = slog[p];
    float temp = fminf(fmaxf(temp_p[0], 0.1f), 5.0f);
    float budget = (float)budget_p[0];
    float inv_t = 1.0f / temp;
    float m = -INFINITY;
    #pragma unroll
    for (int p = 0; p < PP; ++p) { logit[p] *= inv_t; m = fmaxf(m, logit[p]); }
    float e[PP], se = 0.f;
    #pragma unroll
    for (int p = 0; p < PP; ++p) { e[p] = expf(logit[p] - m); se += e[p]; }
    float probs[PP];
    float inv_se = 1.0f / se;
    #pragma unroll
    for (int p = 0; p < PP; ++p) probs[p] = e[p] * inv_se;

    float x[PP], sx = 0.f;
    #pragma unroll
    for (int p = 0; p < PP; ++p) {
        x[p] = fminf(fmaxf(probs[p] * budget, 2.0f), 8.0f);
        sx += x[p];
    }
    float r = budget / (sx + 1e-8f);
    float bits[PP], sb = 0.f;
    #pragma unroll
    for (int p = 0; p < PP; ++p) {
        x[p] *= r;
        bits[p] = rintf(x[p]);   // round-half-even == jnp.round
        sb += bits[p];
    }
    float diff = truncf(budget - sb);
    if (diff != 0.f) {
        int idx = 0;
        if (diff > 0.f) {
            float best = bits[0];
            for (int p = 1; p < PP; ++p) if (bits[p] > best) { best = bits[p]; idx = p; }
        } else {
            float best = bits[0];
            for (int p = 1; p < PP; ++p) if (bits[p] < best) { best = bits[p]; idx = p; }
        }
        bits[idx] = fminf(fmaxf(bits[idx] + diff, 2.0f), 8.0f);
    }

    if (t < PP)            out[b * PP + t] = bits[t];
    else if (t < 2 * PP)   out[BB * PP + b * PP + (t - PP)] = probs[t - PP];
}

extern "C" void kernel_launch(void* const* d_in, const int* in_sizes, int n_in,
                              void* d_out, int out_size, void* d_ws, size_t ws_size,
                              hipStream_t stream) {
    const float* hs     = (const float*)d_in[0];
    const float* W1     = (const float*)d_in[1];
    const float* b1     = (const float*)d_in[2];
    const float* W2     = (const float*)d_in[3];
    const float* b2     = (const float*)d_in[4];
    const float* temp   = (const float*)d_in[5];
    const int*   budget = (const int*)d_in[6];
    float* out = (float*)d_out;

    float* ws   = (float*)d_ws;
    float* part = ws;                                 // BB*SPLIT*HH floats (4 MB)
    float* hbuf = ws + (size_t)BB * SPLIT * HH;       // BB*HH floats

    hipLaunchKernelGGL(pool_partial_k, dim3(BB * SPLIT), dim3(256), 0, stream, hs, part);
    hipLaunchKernelGGL(gemm_fused_k,   dim3(256), dim3(512), 0, stream, part, W1, b1, hbuf);
    hipLaunchKernelGGL(head_k,         dim3(BB), dim3(256), 0, stream, hbuf, W2, b2, temp, budget, out);
}

// Round 9
// 102.498 us; speedup vs baseline: 1.9412x; 1.0483x over previous
//
#include <hip/hip_runtime.h>
#include <math.h>

#define BB 64
#define SS 2048
#define HH 1024
#define PP 8
#define SPLIT 16
#define ROWS (SS / SPLIT)   // 128

typedef float vf4 __attribute__((ext_vector_type(4)));

// ---------------- Kernel 1: partial mean-pool over S ----------------
// R4-EXACT (best measured: 102.6us total): NT loads, 2 accumulator chains,
// s+=2, unroll 4. NT worth ~12-17us vs cached (R4/R5 A/B). No device-fence
// fusion (R7: +92us).
__global__ __launch_bounds__(256) void pool_partial_k(const float* __restrict__ hs,
                                                      float* __restrict__ part) {
    int blk = blockIdx.x;
    int b  = blk / SPLIT;
    int sp = blk % SPLIT;
    int t  = threadIdx.x;
    const vf4* base = reinterpret_cast<const vf4*>(
        hs + (size_t)b * SS * HH + (size_t)sp * ROWS * HH) + t;
    vf4 acc0 = (vf4)0.f;
    vf4 acc1 = (vf4)0.f;
    #pragma unroll 4
    for (int s = 0; s < ROWS; s += 2) {
        vf4 v0 = __builtin_nontemporal_load(&base[(size_t)(s + 0) * (HH / 4)]);
        vf4 v1 = __builtin_nontemporal_load(&base[(size_t)(s + 1) * (HH / 4)]);
        acc0 += v0;
        acc1 += v1;
    }
    reinterpret_cast<vf4*>(part)[(size_t)blk * (HH / 4) + t] = acc0 + acc1;
}

// ---------------- Kernel 2: fused pool-finish + GEMM1 + SiLU ----------------
// R4-EXACT gemm: two-pass i-loop, spool reads NOT hoisted (R8 A/B: hoisting
// measured +4.8us — likely register-pressure/stream-interleave effect).
// grid = 256 blocks: (bg 0..15) x (oc 0..15). 512 threads = 8 waves.
__global__ __launch_bounds__(512) void gemm_fused_k(const float* __restrict__ part,
                                                    const float* __restrict__ W1,
                                                    const float* __restrict__ b1,
                                                    float* __restrict__ hbuf) {
    int bg = blockIdx.x >> 4;
    int oc = blockIdx.x & 15;
    int t  = threadIdx.x;            // 0..511
    int wave = t >> 6, lane = t & 63;
    __shared__ vf4 spool[4][HH / 4];

    // ---- pool finish: pooled rows 4*bg..4*bg+3 from partials ----
    {
        int c  = t & 255;
        int r0 = t >> 8;             // 0..1
        #pragma unroll
        for (int rr = 0; rr < 2; ++rr) {
            int r = r0 + 2 * rr;     // 0..3
            int b = bg * 4 + r;
            const vf4* pb = reinterpret_cast<const vf4*>(part) +
                            (size_t)b * SPLIT * (HH / 4) + c;
            vf4 s = (vf4)0.f;
            #pragma unroll
            for (int sp = 0; sp < SPLIT; ++sp)
                s += pb[(size_t)sp * (HH / 4)];
            spool[r][c] = s * (1.0f / (float)SS);
        }
    }
    __syncthreads();

    // ---- GEMM: wave computes outputs wave*8..wave*8+7; 16-lane K-split ----
    int g = lane >> 4;               // 0..3: output-row group
    int q = lane & 15;               // K-split index within group
    #pragma unroll
    for (int i = 0; i < 2; ++i) {
        int o = oc * 64 + wave * 8 + i * 4 + g;
        const vf4* wrow = reinterpret_cast<const vf4*>(W1 + (size_t)o * HH);
        float s0 = 0.f, s1 = 0.f, s2 = 0.f, s3 = 0.f;
        #pragma unroll
        for (int k = 0; k < 16; ++k) {
            vf4 wv = wrow[q + 16 * k];
            vf4 p0 = spool[0][q + 16 * k];
            vf4 p1 = spool[1][q + 16 * k];
            vf4 p2 = spool[2][q + 16 * k];
            vf4 p3 = spool[3][q + 16 * k];
            s0 += wv.x * p0.x + wv.y * p0.y + wv.z * p0.z + wv.w * p0.w;
            s1 += wv.x * p1.x + wv.y * p1.y + wv.z * p1.z + wv.w * p1.w;
            s2 += wv.x * p2.x + wv.y * p2.y + wv.z * p2.z + wv.w * p2.w;
            s3 += wv.x * p3.x + wv.y * p3.y + wv.z * p3.z + wv.w * p3.w;
        }
        #pragma unroll
        for (int off = 1; off < 16; off <<= 1) {   // butterfly within 16-lane group
            s0 += __shfl_xor(s0, off);
            s1 += __shfl_xor(s1, off);
            s2 += __shfl_xor(s2, off);
            s3 += __shfl_xor(s3, off);
        }
        if (q < 4) {                 // lane q of group g writes batch row q
            float s = (q == 0) ? s0 : ((q == 1) ? s1 : ((q == 2) ? s2 : s3));
            int b = bg * 4 + q;
            float z = s + b1[o];
            hbuf[(size_t)b * HH + o] = z / (1.f + expf(-z));
        }
    }
}

// ---------------- Kernel 3: logits, softmax, bit allocation ----------------
// grid = BB blocks, 256 threads (4 waves). Wave w computes logits p=2w,2w+1.
__global__ __launch_bounds__(256) void head_k(const float* __restrict__ hbuf,
                                              const float* __restrict__ W2,
                                              const float* __restrict__ b2,
                                              const float* __restrict__ temp_p,
                                              const int* __restrict__ budget_p,
                                              float* __restrict__ out) {
    int b = blockIdx.x;
    int t = threadIdx.x;
    int wave = t >> 6, lane = t & 63;
    __shared__ float slog[PP];

    {
        const vf4* hrow = reinterpret_cast<const vf4*>(hbuf + (size_t)b * HH);
        int p0 = wave * 2, p1 = wave * 2 + 1;
        const vf4* w0 = reinterpret_cast<const vf4*>(W2 + (size_t)p0 * HH);
        const vf4* w1 = reinterpret_cast<const vf4*>(W2 + (size_t)p1 * HH);
        float s0 = 0.f, s1 = 0.f;
        #pragma unroll
        for (int k = 0; k < 4; ++k) {
            vf4 hv = hrow[lane + 64 * k];
            vf4 a = w0[lane + 64 * k];
            vf4 c = w1[lane + 64 * k];
            s0 += a.x * hv.x + a.y * hv.y + a.z * hv.z + a.w * hv.w;
            s1 += c.x * hv.x + c.y * hv.y + c.z * hv.z + c.w * hv.w;
        }
        #pragma unroll
        for (int off = 32; off; off >>= 1) {
            s0 += __shfl_xor(s0, off);
            s1 += __shfl_xor(s1, off);
        }
        if (lane == 0) {
            slog[p0] = s0 + b2[p0];
            slog[p1] = s1 + b2[p1];
        }
    }
    __syncthreads();
    if (wave != 0) return;

    float logit[PP];
    #pragma unroll
    for (int p = 0; p < PP; ++p) logit[p] = slog[p];
    float temp = fminf(fmaxf(temp_p[0], 0.1f), 5.0f);
    float budget = (float)budget_p[0];
    float inv_t = 1.0f / temp;
    float m = -INFINITY;
    #pragma unroll
    for (int p = 0; p < PP; ++p) { logit[p] *= inv_t; m = fmaxf(m, logit[p]); }
    float e[PP], se = 0.f;
    #pragma unroll
    for (int p = 0; p < PP; ++p) { e[p] = expf(logit[p] - m); se += e[p]; }
    float probs[PP];
    float inv_se = 1.0f / se;
    #pragma unroll
    for (int p = 0; p < PP; ++p) probs[p] = e[p] * inv_se;

    float x[PP], sx = 0.f;
    #pragma unroll
    for (int p = 0; p < PP; ++p) {
        x[p] = fminf(fmaxf(probs[p] * budget, 2.0f), 8.0f);
        sx += x[p];
    }
    float r = budget / (sx + 1e-8f);
    float bits[PP], sb = 0.f;
    #pragma unroll
    for (int p = 0; p < PP; ++p) {
        x[p] *= r;
        bits[p] = rintf(x[p]);   // round-half-even == jnp.round
        sb += bits[p];
    }
    float diff = truncf(budget - sb);
    if (diff != 0.f) {
        int idx = 0;
        if (diff > 0.f) {
            float best = bits[0];
            for (int p = 1; p < PP; ++p) if (bits[p] > best) { best = bits[p]; idx = p; }
        } else {
            float best = bits[0];
            for (int p = 1; p < PP; ++p) if (bits[p] < best) { best = bits[p]; idx = p; }
        }
        bits[idx] = fminf(fmaxf(bits[idx] + diff, 2.0f), 8.0f);
    }

    if (t < PP)            out[b * PP + t] = bits[t];
    else if (t < 2 * PP)   out[BB * PP + b * PP + (t - PP)] = probs[t - PP];
}

extern "C" void kernel_launch(void* const* d_in, const int* in_sizes, int n_in,
                              void* d_out, int out_size, void* d_ws, size_t ws_size,
                              hipStream_t stream) {
    const float* hs     = (const float*)d_in[0];
    const float* W1     = (const float*)d_in[1];
    const float* b1     = (const float*)d_in[2];
    const float* W2     = (const float*)d_in[3];
    const float* b2     = (const float*)d_in[4];
    const float* temp   = (const float*)d_in[5];
    const int*   budget = (const int*)d_in[6];
    float* out = (float*)d_out;

    float* ws   = (float*)d_ws;
    float* part = ws;                                 // BB*SPLIT*HH floats (4 MB)
    float* hbuf = ws + (size_t)BB * SPLIT * HH;       // BB*HH floats

    hipLaunchKernelGGL(pool_partial_k, dim3(BB * SPLIT), dim3(256), 0, stream, hs, part);
    hipLaunchKernelGGL(gemm_fused_k,   dim3(256), dim3(512), 0, stream, part, W1, b1, hbuf);
    hipLaunchKernelGGL(head_k,         dim3(BB), dim3(256), 0, stream, hbuf, W2, b2, temp, budget, out);
}